// Round 1
// 2316.496 us; speedup vs baseline: 1.5500x; 1.5500x over previous
//
#include <hip/hip_runtime.h>
#include <hip/hip_bf16.h>

#define B_ 2
#define S_ 1024
#define D_ 768
#define H_ 12
#define DH_ 64
#define L_ 6
#define F_ 3072
#define R_ 32

typedef __attribute__((ext_vector_type(8))) short short8;
typedef __attribute__((ext_vector_type(4))) float floatx4;

static __device__ __forceinline__ float b2f(__hip_bfloat16 x) { return __bfloat162float(x); }
static __device__ __forceinline__ unsigned short f2bu(float x) {
  __hip_bfloat16 h = __float2bfloat16(x);
  return *(unsigned short*)&h;
}
static __device__ __forceinline__ float u2f(unsigned short u) {
  __hip_bfloat16 h; *(unsigned short*)&h = u; return __bfloat162float(h);
}

// ---------------- embedding -> x (f32, lives in d_out) ----------------
__global__ __launch_bounds__(256) void embed_kernel(
    const int* __restrict__ tok, const int* __restrict__ seg,
    const int* __restrict__ pos, const int* __restrict__ qm,
    const float* __restrict__ tok_emb, const float* __restrict__ seg_emb,
    float* __restrict__ x) {
  int row = blockIdx.x;              // b*S + s
  int t = tok[row], sg = seg[row], q = qm[row];
  int p = pos[row] * q;
  float fq = (float)q;
  for (int d = threadIdx.x; d < D_; d += 256) {
    float val = tok_emb[(size_t)t * D_ + d] + seg_emb[(size_t)sg * D_ + d];
    float e = (float)(2 * (d / 2)) / (float)D_;
    float ang = (float)p / powf(10000.0f, e);
    float pt = ((d & 1) == 0) ? sinf(ang) : cosf(ang);
    x[(size_t)row * D_ + d] = val + pt * fq;
  }
}

// ---------------- layernorm: x f32 -> y bf16 ----------------
__global__ __launch_bounds__(256) void ln_kernel(
    const float* __restrict__ X, const float* __restrict__ g,
    const float* __restrict__ bta, __hip_bfloat16* __restrict__ Y) {
  __shared__ float red[256];
  int row = blockIdx.x;
  int tid = threadIdx.x;
  const float* xr = X + (size_t)row * D_;
  float x0 = xr[tid], x1 = xr[tid + 256], x2 = xr[tid + 512];
  red[tid] = x0 + x1 + x2;
  __syncthreads();
  for (int s = 128; s > 0; s >>= 1) { if (tid < s) red[tid] += red[tid + s]; __syncthreads(); }
  float mu = red[0] * (1.0f / 768.0f);
  __syncthreads();
  float d0 = x0 - mu, d1 = x1 - mu, d2 = x2 - mu;
  red[tid] = d0 * d0 + d1 * d1 + d2 * d2;
  __syncthreads();
  for (int s = 128; s > 0; s >>= 1) { if (tid < s) red[tid] += red[tid + s]; __syncthreads(); }
  float var = red[0] * (1.0f / 768.0f);
  float rs = rsqrtf(var + 1e-12f);
  size_t base = (size_t)row * D_;
  Y[base + tid]       = __float2bfloat16(d0 * rs * g[tid]       + bta[tid]);
  Y[base + tid + 256] = __float2bfloat16(d1 * rs * g[tid + 256] + bta[tid + 256]);
  Y[base + tid + 512] = __float2bfloat16(d2 * rs * g[tid + 512] + bta[tid + 512]);
}

// ---------------- MFMA GEMM body: C[M,N] = op(A[M,K](bf16) @ W[K,N](f32->bf16) + bias) ----
// flags: bit0 = residual add into f32 C, bit1 = gelu(tanh), bit3 = C bf16 store
#define GF_RES 1
#define GF_GELU 2
#define GF_BF16OUT 8

__device__ __forceinline__ void gemm_body(
    short* __restrict__ sA, short* __restrict__ sB,
    const __hip_bfloat16* __restrict__ A, const float* __restrict__ W,
    const float* __restrict__ bias, void* __restrict__ C,
    int N, int K, int flags) {
  int t = threadIdx.x;
  int w = t >> 6, lane = t & 63;
  int wm = w >> 1, wn = w & 1;
  int q4 = lane >> 4, l16 = lane & 15;
  int m0 = blockIdx.y * 128, n0 = blockIdx.x * 128;

  floatx4 acc[4][4] = {};

  int arow = t >> 1, ahalf = t & 1;       // A staging: 128 rows x 32 k
  int wk = t >> 3, ng = (t & 7) * 16;     // W staging: 32 k x 128 n

  for (int k0 = 0; k0 < K; k0 += 32) {
    // stage A: 16 bf16 per thread (two 16B chunks = kquads ahalf*2, ahalf*2+1)
    const uint4* ga = (const uint4*)(A + (size_t)(m0 + arow) * K + k0 + ahalf * 16);
    uint4 a0 = ga[0];
    uint4 a1 = ga[1];
    *(uint4*)&sA[((ahalf * 2 + 0) * 128 + arow) * 8] = a0;
    *(uint4*)&sA[((ahalf * 2 + 1) * 128 + arow) * 8] = a1;
    // stage W: 16 f32 per thread, convert to bf16, transposed store
    const float* gw = W + (size_t)(k0 + wk) * N + n0 + ng;
    int qq = wk >> 3, ki = wk & 7;
#pragma unroll
    for (int e = 0; e < 16; ++e) {
      sB[((qq * 128 + ng + e)) * 8 + ki] = (short)f2bu(gw[e]);
    }
    __syncthreads();
    short8 af[4], bf[4];
#pragma unroll
    for (int mt = 0; mt < 4; ++mt)
      af[mt] = *(short8*)&sA[(q4 * 128 + wm * 64 + mt * 16 + l16) * 8];
#pragma unroll
    for (int nt = 0; nt < 4; ++nt)
      bf[nt] = *(short8*)&sB[(q4 * 128 + wn * 64 + nt * 16 + l16) * 8];
#pragma unroll
    for (int mt = 0; mt < 4; ++mt)
#pragma unroll
      for (int nt = 0; nt < 4; ++nt)
        acc[mt][nt] = __builtin_amdgcn_mfma_f32_16x16x32_bf16(af[mt], bf[nt], acc[mt][nt], 0, 0, 0);
    __syncthreads();
  }

#pragma unroll
  for (int mt = 0; mt < 4; ++mt) {
#pragma unroll
    for (int nt = 0; nt < 4; ++nt) {
      int col = n0 + wn * 64 + nt * 16 + l16;
      float bv = bias[col];
#pragma unroll
      for (int r = 0; r < 4; ++r) {
        int row = m0 + wm * 64 + mt * 16 + q4 * 4 + r;
        float val = acc[mt][nt][r] + bv;
        if (flags & GF_GELU) {
          float u = val;
          float c = 0.7978845608028654f * (u + 0.044715f * u * u * u);
          val = 0.5f * u * (1.0f + tanhf(c));
        }
        size_t idx = (size_t)row * N + col;
        if (flags & GF_BF16OUT) {
          ((__hip_bfloat16*)C)[idx] = __float2bfloat16(val);
        } else if (flags & GF_RES) {
          ((float*)C)[idx] += val;
        } else {
          ((float*)C)[idx] = val;
        }
      }
    }
  }
}

__global__ __launch_bounds__(256) void gemm_mfma(
    const __hip_bfloat16* __restrict__ A, const float* __restrict__ W,
    const float* __restrict__ bias, void* __restrict__ C,
    int N, int K, int flags) {
  __shared__ short sA[4 * 128 * 8];
  __shared__ short sB[4 * 128 * 8];
  gemm_body(sA, sB, A, W, bias, C, N, K, flags);
}

// batched Q/K/V projection: blockIdx.z selects which weight/bias/output
__global__ __launch_bounds__(256) void gemm_qkv(
    const __hip_bfloat16* __restrict__ A,
    const float* __restrict__ W0, const float* __restrict__ W1, const float* __restrict__ W2,
    const float* __restrict__ b0, const float* __restrict__ b1, const float* __restrict__ b2,
    void* __restrict__ C0, void* __restrict__ C1, void* __restrict__ C2,
    int N, int K, int flags) {
  __shared__ short sA[4 * 128 * 8];
  __shared__ short sB[4 * 128 * 8];
  int z = blockIdx.z;
  const float* W = (z == 0) ? W0 : (z == 1) ? W1 : W2;
  const float* bb = (z == 0) ? b0 : (z == 1) ? b1 : b2;
  void* C = (z == 0) ? C0 : (z == 1) ? C1 : C2;
  gemm_body(sA, sB, A, W, bb, C, N, K, flags);
}

// ---------------- MFMA flash attention: block = (64 queries, h, b), 4 waves ----------------
// LDS tiles are [row][64] bf16 with 16B-granularity XOR swizzle (idx in shorts):
#define SWZ(r, c) ((((r) * 64) + (c)) ^ (((r) & 7) << 3))

__global__ __launch_bounds__(256) void attn_mfma(
    const __hip_bfloat16* __restrict__ q, const __hip_bfloat16* __restrict__ k,
    const __hip_bfloat16* __restrict__ v, const float* __restrict__ rel_emb,
    const int* __restrict__ rel_ids, const int* __restrict__ att_mask,
    __hip_bfloat16* __restrict__ ctx) {
  __shared__ __align__(16) short QsSs[64 * 64];  // Q tile, then reused for P tile
  __shared__ __align__(16) short Ks[64 * 64];
  __shared__ __align__(16) short Vt[64 * 64];    // transposed V: [d][j]
  __shared__ float relb[64 * 32];                // pre-scaled rel bias [i][r]

  int t = threadIdx.x;
  int w = t >> 6, lane = t & 63;
  int g = lane >> 4, l16 = lane & 15;
  int i0 = blockIdx.x * 64, h = blockIdx.y, b = blockIdx.z;

  // ---- stage Q tile, folding in the 1/8 softmax scale (exact in bf16) ----
  {
    int row = lane;
    const __hip_bfloat16* src = q + ((size_t)(b * S_ + i0 + row)) * D_ + h * DH_ + w * 16;
    uint4 u0 = *(const uint4*)src;
    uint4 u1 = *(const uint4*)(src + 8);
    const unsigned short* p0 = (const unsigned short*)&u0;
    const unsigned short* p1 = (const unsigned short*)&u1;
    short8 t0, t1;
#pragma unroll
    for (int e = 0; e < 8; ++e) t0[e] = (short)f2bu(u2f(p0[e]) * 0.125f);
#pragma unroll
    for (int e = 0; e < 8; ++e) t1[e] = (short)f2bu(u2f(p1[e]) * 0.125f);
    *(short8*)&QsSs[SWZ(row, w * 16)]     = t0;
    *(short8*)&QsSs[SWZ(row, w * 16 + 8)] = t1;
  }
  __syncthreads();

  // ---- per-wave Q fragments (rows w*16..w*16+15), hoisted for whole kernel ----
  short8 afq[2];
  afq[0] = *(short8*)&QsSs[SWZ(w * 16 + l16, 0 + g * 8)];
  afq[1] = *(short8*)&QsSs[SWZ(w * 16 + l16, 32 + g * 8)];

  // ---- rel bias table via MFMA: relb[i][r] = (Q/8)[i] . rel_emb[r][h] ----
  {
    floatx4 racc[2] = {};
#pragma unroll
    for (int rsub = 0; rsub < 2; ++rsub) {
      int r = rsub * 16 + l16;
#pragma unroll
      for (int ks = 0; ks < 2; ++ks) {
        const float* rp = rel_emb + ((size_t)r * H_ + h) * DH_ + ks * 32 + g * 8;
        short8 brf;
#pragma unroll
        for (int e = 0; e < 8; ++e) brf[e] = (short)f2bu(rp[e]);
        racc[rsub] = __builtin_amdgcn_mfma_f32_16x16x32_bf16(afq[ks], brf, racc[rsub], 0, 0, 0);
      }
    }
#pragma unroll
    for (int rsub = 0; rsub < 2; ++rsub)
#pragma unroll
      for (int rr = 0; rr < 4; ++rr)
        relb[(w * 16 + g * 4 + rr) * 32 + rsub * 16 + l16] = racc[rsub][rr];
  }
  __syncthreads();  // Q reads done -> QsSs becomes the P buffer

  float m_old[4] = {-1e30f, -1e30f, -1e30f, -1e30f};
  float lsum[4] = {0.0f, 0.0f, 0.0f, 0.0f};
  floatx4 oacc[4] = {};

  for (int jt = 0; jt < S_ / 64; ++jt) {
    int j0 = jt * 64;
    // stage K tile (row-major, swizzled)
    {
      int row = lane;
      const __hip_bfloat16* src = k + ((size_t)(b * S_ + j0 + row)) * D_ + h * DH_ + w * 16;
      uint4 u0 = *(const uint4*)src;
      uint4 u1 = *(const uint4*)(src + 8);
      *(uint4*)&Ks[SWZ(row, w * 16)]     = u0;
      *(uint4*)&Ks[SWZ(row, w * 16 + 8)] = u1;
    }
    // stage V transposed: wave w owns d-rows w*16..w*16+15; lanes span j -> one
    // contiguous 128B LDS row per scalar-store instruction (conflict-free)
    {
      int j = lane;
      const __hip_bfloat16* src = v + ((size_t)(b * S_ + j0 + j)) * D_ + h * DH_ + w * 16;
      uint4 u0 = *(const uint4*)src;
      uint4 u1 = *(const uint4*)(src + 8);
      const unsigned short* p0 = (const unsigned short*)&u0;
      const unsigned short* p1 = (const unsigned short*)&u1;
#pragma unroll
      for (int e = 0; e < 8; ++e) Vt[SWZ(w * 16 + e, j)] = (short)p0[e];
#pragma unroll
      for (int e = 0; e < 8; ++e) Vt[SWZ(w * 16 + 8 + e, j)] = (short)p1[e];
    }
    __syncthreads();

    // QK^T: wave's 16 i-rows x 64 j-cols, pre-scaled by 1/8 via Q
    floatx4 sacc[4] = {};
#pragma unroll
    for (int ks = 0; ks < 2; ++ks)
#pragma unroll
      for (int jm = 0; jm < 4; ++jm) {
        short8 bk = *(short8*)&Ks[SWZ(jm * 16 + l16, ks * 32 + g * 8)];
        sacc[jm] = __builtin_amdgcn_mfma_f32_16x16x32_bf16(afq[ks], bk, sacc[jm], 0, 0, 0);
      }

    // rel-bias gather + mask + online softmax; write P (bf16) into wave's Ss stripe
    float alpha[4];
#pragma unroll
    for (int r = 0; r < 4; ++r) {
      int gi = i0 + w * 16 + g * 4 + r;
      const int* ridp = rel_ids + ((size_t)(b * S_ + gi)) * S_ + j0 + l16;
      const int* amp  = att_mask + ((size_t)(b * S_ + gi)) * S_ + j0 + l16;
      const float* rbrow = relb + (w * 16 + g * 4 + r) * 32;
      float sv[4];
      float tmax = -3e38f;
#pragma unroll
      for (int jm = 0; jm < 4; ++jm) {
        int rid = ridp[jm * 16];
        int am  = amp[jm * 16];
        float sc = sacc[jm][r] + rbrow[rid] + (am ? 0.0f : -10000.0f);
        sv[jm] = sc;
        tmax = fmaxf(tmax, sc);
      }
#pragma unroll
      for (int off = 1; off < 16; off <<= 1) tmax = fmaxf(tmax, __shfl_xor(tmax, off));
      float mn = fmaxf(m_old[r], tmax);
      float al = __expf(m_old[r] - mn);
      m_old[r] = mn;
      float ps = 0.0f;
#pragma unroll
      for (int jm = 0; jm < 4; ++jm) {
        unsigned short pu = f2bu(__expf(sv[jm] - mn));
        QsSs[SWZ(w * 16 + g * 4 + r, jm * 16 + l16)] = (short)pu;
        ps += u2f(pu);  // lsum consistent with the bf16 P actually used in PV
      }
#pragma unroll
      for (int off = 1; off < 16; off <<= 1) ps += __shfl_xor(ps, off);
      lsum[r] = lsum[r] * al + ps;
      alpha[r] = al;
    }
#pragma unroll
    for (int dt = 0; dt < 4; ++dt)
#pragma unroll
      for (int r = 0; r < 4; ++r) oacc[dt][r] *= alpha[r];

    // PV: A = P (wave-private Ss stripe), B = Vt
#pragma unroll
    for (int ks = 0; ks < 2; ++ks) {
      short8 ap = *(short8*)&QsSs[SWZ(w * 16 + l16, ks * 32 + g * 8)];
#pragma unroll
      for (int dt = 0; dt < 4; ++dt) {
        short8 bv_ = *(short8*)&Vt[SWZ(dt * 16 + l16, ks * 32 + g * 8)];
        oacc[dt] = __builtin_amdgcn_mfma_f32_16x16x32_bf16(ap, bv_, oacc[dt], 0, 0, 0);
      }
    }
    __syncthreads();  // before next tile overwrites Ks/Vt
  }

  // normalize + store ctx (bf16)
#pragma unroll
  for (int r = 0; r < 4; ++r) {
    float inv = 1.0f / lsum[r];
    int gi = i0 + w * 16 + g * 4 + r;
    __hip_bfloat16* dst = ctx + ((size_t)(b * S_ + gi)) * D_ + h * DH_;
#pragma unroll
    for (int dt = 0; dt < 4; ++dt) {
      unsigned short pv = f2bu(oacc[dt][r] * inv);
      *(unsigned short*)&dst[dt * 16 + l16] = pv;
    }
  }
}

extern "C" void kernel_launch(void* const* d_in, const int* in_sizes, int n_in,
                              void* d_out, int out_size, void* d_ws, size_t ws_size,
                              hipStream_t stream) {
  const int* token_ids    = (const int*)d_in[0];
  const int* segment_ids  = (const int*)d_in[1];
  const int* position_ids = (const int*)d_in[2];
  const int* question_mask= (const int*)d_in[3];
  const int* att_mask     = (const int*)d_in[4];
  const int* rel_ids      = (const int*)d_in[5];
  const float* tok_emb = (const float*)d_in[6];
  const float* seg_emb = (const float*)d_in[7];
  const float* ln1_g = (const float*)d_in[8];
  const float* ln1_b = (const float*)d_in[9];
  const float* ln2_g = (const float*)d_in[10];
  const float* ln2_b = (const float*)d_in[11];
  const float* wq = (const float*)d_in[12];
  const float* bq = (const float*)d_in[13];
  const float* wk = (const float*)d_in[14];
  const float* bk = (const float*)d_in[15];
  const float* wv = (const float*)d_in[16];
  const float* bv = (const float*)d_in[17];
  const float* wo = (const float*)d_in[18];
  const float* bo = (const float*)d_in[19];
  const float* rel_emb = (const float*)d_in[20];
  const float* w1 = (const float*)d_in[21];
  const float* b1 = (const float*)d_in[22];
  const float* w2 = (const float*)d_in[23];
  const float* b2 = (const float*)d_in[24];

  const size_t NTOK = (size_t)B_ * S_ * D_;     // 1,572,864 elems
  const size_t BF = NTOK * 2;                   // bytes per bf16 activation

  float* x = (float*)d_out;                     // residual stream f32 in d_out
  char* ws = (char*)d_ws;
  __hip_bfloat16* h = (__hip_bfloat16*)(ws);
  __hip_bfloat16* q = (__hip_bfloat16*)(ws + BF);
  __hip_bfloat16* k = (__hip_bfloat16*)(ws + 2 * BF);
  __hip_bfloat16* v = (__hip_bfloat16*)(ws + 3 * BF);
  // ffn (B*S*F bf16 = 12.58MB) aliases q,k,v (dead during FFN) + 3.15MB; peak 15.73MB
  __hip_bfloat16* ffn = (__hip_bfloat16*)(ws + BF);

  embed_kernel<<<B_ * S_, 256, 0, stream>>>(token_ids, segment_ids, position_ids,
                                            question_mask, tok_emb, seg_emb, x);

  dim3 gProj(D_ / 128, (B_ * S_) / 128);        // (6, 16)
  dim3 gQkv(D_ / 128, (B_ * S_) / 128, 3);      // (6, 16, 3) batched q/k/v
  dim3 gFfn1(F_ / 128, (B_ * S_) / 128);        // (24, 16)
  dim3 gAttn(S_ / 64, H_, B_);                  // (16, 12, 2)

  for (int l = 0; l < L_; ++l) {
    const float* wq_l = wq + (size_t)l * D_ * D_;
    const float* wk_l = wk + (size_t)l * D_ * D_;
    const float* wv_l = wv + (size_t)l * D_ * D_;
    const float* wo_l = wo + (size_t)l * D_ * D_;
    const float* w1_l = w1 + (size_t)l * D_ * F_;
    const float* w2_l = w2 + (size_t)l * F_ * D_;
    const float* re_l = rel_emb + (size_t)l * R_ * H_ * DH_;

    ln_kernel<<<B_ * S_, 256, 0, stream>>>(x, ln1_g + (size_t)l * D_, ln1_b + (size_t)l * D_, h);
    gemm_qkv<<<gQkv, 256, 0, stream>>>(h, wq_l, wk_l, wv_l,
                                       bq + (size_t)l * D_, bk + (size_t)l * D_, bv + (size_t)l * D_,
                                       q, k, v, D_, D_, GF_BF16OUT);
    attn_mfma<<<gAttn, 256, 0, stream>>>(q, k, v, re_l, rel_ids, att_mask, h);
    gemm_mfma<<<gProj, 256, 0, stream>>>(h, wo_l, bo + (size_t)l * D_, x, D_, D_, GF_RES);
    ln_kernel<<<B_ * S_, 256, 0, stream>>>(x, ln2_g + (size_t)l * D_, ln2_b + (size_t)l * D_, h);
    gemm_mfma<<<gFfn1, 256, 0, stream>>>(h, w1_l, b1 + (size_t)l * F_, ffn, F_, D_,
                                         GF_GELU | GF_BF16OUT);
    gemm_mfma<<<gProj, 256, 0, stream>>>(ffn, w2_l, b2 + (size_t)l * D_, x, D_, F_, GF_RES);
  }
  // x == d_out (f32): done.
}

// Round 2
// 1444.154 us; speedup vs baseline: 2.4863x; 1.6040x over previous
//
#include <hip/hip_runtime.h>
#include <hip/hip_bf16.h>

#define B_ 2
#define S_ 1024
#define D_ 768
#define H_ 12
#define DH_ 64
#define L_ 6
#define F_ 3072
#define R_ 32

typedef __attribute__((ext_vector_type(8))) short short8;
typedef __attribute__((ext_vector_type(4))) float floatx4;

static __device__ __forceinline__ float b2f(__hip_bfloat16 x) { return __bfloat162float(x); }
static __device__ __forceinline__ unsigned short f2bu(float x) {
  __hip_bfloat16 h = __float2bfloat16(x);
  return *(unsigned short*)&h;
}
static __device__ __forceinline__ float u2f(unsigned short u) {
  __hip_bfloat16 h; *(unsigned short*)&h = u; return __bfloat162float(h);
}

// async global->LDS, 16B per lane; LDS dest must be wave-uniform (base + lane*16)
static __device__ __forceinline__ void gld_lds16(const void* g, void* l) {
  __builtin_amdgcn_global_load_lds(
      (const __attribute__((address_space(1))) void*)g,
      (__attribute__((address_space(3))) void*)l, 16, 0, 0);
}

// ---------------- embedding -> x (f32, lives in d_out) ----------------
__global__ __launch_bounds__(256) void embed_kernel(
    const int* __restrict__ tok, const int* __restrict__ seg,
    const int* __restrict__ pos, const int* __restrict__ qm,
    const float* __restrict__ tok_emb, const float* __restrict__ seg_emb,
    float* __restrict__ x) {
  int row = blockIdx.x;              // b*S + s
  int t = tok[row], sg = seg[row], q = qm[row];
  int p = pos[row] * q;
  float fq = (float)q;
  for (int d = threadIdx.x; d < D_; d += 256) {
    float val = tok_emb[(size_t)t * D_ + d] + seg_emb[(size_t)sg * D_ + d];
    float e = (float)(2 * (d / 2)) / (float)D_;
    float ang = (float)p / powf(10000.0f, e);
    float pt = ((d & 1) == 0) ? sinf(ang) : cosf(ang);
    x[(size_t)row * D_ + d] = val + pt * fq;
  }
}

// ---------------- layernorm: x f32 -> y bf16 ----------------
__global__ __launch_bounds__(256) void ln_kernel(
    const float* __restrict__ X, const float* __restrict__ g,
    const float* __restrict__ bta, __hip_bfloat16* __restrict__ Y) {
  __shared__ float red[256];
  int row = blockIdx.x;
  int tid = threadIdx.x;
  const float* xr = X + (size_t)row * D_;
  float x0 = xr[tid], x1 = xr[tid + 256], x2 = xr[tid + 512];
  red[tid] = x0 + x1 + x2;
  __syncthreads();
  for (int s = 128; s > 0; s >>= 1) { if (tid < s) red[tid] += red[tid + s]; __syncthreads(); }
  float mu = red[0] * (1.0f / 768.0f);
  __syncthreads();
  float d0 = x0 - mu, d1 = x1 - mu, d2 = x2 - mu;
  red[tid] = d0 * d0 + d1 * d1 + d2 * d2;
  __syncthreads();
  for (int s = 128; s > 0; s >>= 1) { if (tid < s) red[tid] += red[tid + s]; __syncthreads(); }
  float var = red[0] * (1.0f / 768.0f);
  float rs = rsqrtf(var + 1e-12f);
  size_t base = (size_t)row * D_;
  Y[base + tid]       = __float2bfloat16(d0 * rs * g[tid]       + bta[tid]);
  Y[base + tid + 256] = __float2bfloat16(d1 * rs * g[tid + 256] + bta[tid + 256]);
  Y[base + tid + 512] = __float2bfloat16(d2 * rs * g[tid + 512] + bta[tid + 512]);
}

// ---------------- per-layer weight prepack: f32 [K][N] -> bf16 [K/8][N][8] ----------------
// segments (blocks of 256 thr, 1 chunk of 8 k-elems per thread):
// wq/wk/wv/wo: 288 blocks each; w1: 1152; w2: 1152  => 3456 blocks total
#define WOFF_WO 1769472
#define WOFF_W1 2359296
#define WOFF_W2 4718592
#define WELEMS  7077888

__global__ __launch_bounds__(256) void prepack(
    const float* __restrict__ wq, const float* __restrict__ wk,
    const float* __restrict__ wv, const float* __restrict__ wo,
    const float* __restrict__ w1, const float* __restrict__ w2,
    __hip_bfloat16* __restrict__ out) {
  int bid = blockIdx.x;
  const float* src;
  int N;
  size_t obase;
  int c;
  if (bid < 1152) {
    int m = bid / 288;
    int b = bid - m * 288;
    src = (m == 0) ? wq : (m == 1) ? wk : (m == 2) ? wv : wo;
    N = 768; obase = (size_t)m * 589824;
    c = b * 256 + threadIdx.x;
  } else if (bid < 2304) {
    int b = bid - 1152;
    src = w1; N = 3072; obase = WOFF_W1;
    c = b * 256 + threadIdx.x;
  } else {
    int b = bid - 2304;
    src = w2; N = 768; obase = WOFF_W2;
    c = b * 256 + threadIdx.x;
  }
  int kb = c / N, n = c - kb * N;
  short8 o;
#pragma unroll
  for (int j = 0; j < 8; ++j) o[j] = (short)f2bu(src[(size_t)(kb * 8 + j) * N + n]);
  *(short8*)(out + obase + (size_t)c * 8) = o;
}

// ---------------- MFMA GEMM: C[M,N] = op(A[M,K](bf16) @ Wp + bias) ----------------
// Wp is prepacked [K/8][N][8] bf16. flags: bit0 res-atomicAdd f32, bit1 gelu, bit3 bf16 out
#define GF_RES 1
#define GF_GELU 2
#define GF_BF16OUT 8

__device__ __forceinline__ void gemm_core(
    short* sA, short* sB,
    const __hip_bfloat16* __restrict__ A, const __hip_bfloat16* __restrict__ Wp,
    const float* __restrict__ bias, void* __restrict__ C,
    int N, int K, int kbase, int kchunk, bool addb, int flags) {
  int t = threadIdx.x;
  int w = t >> 6, lane = t & 63;
  int wm = w >> 1, wn = w & 1;
  int q4 = lane >> 4, l16 = lane & 15;
  int m0 = blockIdx.y * 128, n0 = blockIdx.x * 128;

  floatx4 acc[4][4] = {};

  for (int k0 = kbase; k0 < kbase + kchunk; k0 += 32) {
    // A tile: wave w stages k-quad w, rows 0..127 (two 64-row chunks)
    gld_lds16(A + (size_t)(m0 + lane) * K + k0 + w * 8,      &sA[(w * 128) * 8]);
    gld_lds16(A + (size_t)(m0 + 64 + lane) * K + k0 + w * 8, &sA[(w * 128 + 64) * 8]);
    // B tile: wave w stages k-quad w, 2KB contiguous (prepacked layout == LDS layout)
    const __hip_bfloat16* gb = Wp + (((size_t)(k0 >> 3) + w) * N + n0) * 8;
    gld_lds16(gb + (size_t)lane * 8,       &sB[w * 1024]);
    gld_lds16(gb + 512 + (size_t)lane * 8, &sB[w * 1024 + 512]);
    __syncthreads();   // drains vmcnt (compiler emits full waitcnt before barrier)

    short8 af[4], bf[4];
#pragma unroll
    for (int mt = 0; mt < 4; ++mt)
      af[mt] = *(short8*)&sA[(q4 * 128 + wm * 64 + mt * 16 + l16) * 8];
#pragma unroll
    for (int nt = 0; nt < 4; ++nt)
      bf[nt] = *(short8*)&sB[(q4 * 128 + wn * 64 + nt * 16 + l16) * 8];
#pragma unroll
    for (int mt = 0; mt < 4; ++mt)
#pragma unroll
      for (int nt = 0; nt < 4; ++nt)
        acc[mt][nt] = __builtin_amdgcn_mfma_f32_16x16x32_bf16(af[mt], bf[nt], acc[mt][nt], 0, 0, 0);
    __syncthreads();
  }

#pragma unroll
  for (int mt = 0; mt < 4; ++mt) {
#pragma unroll
    for (int nt = 0; nt < 4; ++nt) {
      int col = n0 + wn * 64 + nt * 16 + l16;
      float bv = addb ? bias[col] : 0.0f;
#pragma unroll
      for (int r = 0; r < 4; ++r) {
        int row = m0 + wm * 64 + mt * 16 + q4 * 4 + r;
        float val = acc[mt][nt][r] + bv;
        if (flags & GF_GELU) {
          float u = val;
          float c = 0.7978845608028654f * (u + 0.044715f * u * u * u);
          val = 0.5f * u * (1.0f + tanhf(c));
        }
        size_t idx = (size_t)row * N + col;
        if (flags & GF_BF16OUT) {
          ((__hip_bfloat16*)C)[idx] = __float2bfloat16(val);
        } else if (flags & GF_RES) {
          atomicAdd((float*)C + idx, val);   // split-K partials accumulate
        } else {
          ((float*)C)[idx] = val;
        }
      }
    }
  }
}

__global__ __launch_bounds__(256) void gemm_bf16(
    const __hip_bfloat16* __restrict__ A, const __hip_bfloat16* __restrict__ Wp,
    const float* __restrict__ bias, void* __restrict__ C,
    int N, int K, int kchunk, int flags) {
  __shared__ __align__(16) short sA[4 * 128 * 8];
  __shared__ __align__(16) short sB[4 * 128 * 8];
  int kbase = blockIdx.z * kchunk;
  gemm_core(sA, sB, A, Wp, bias, C, N, K, kbase, kchunk, blockIdx.z == 0, flags);
}

// batched Q/K/V projection: blockIdx.z selects which weight/bias/output
__global__ __launch_bounds__(256) void gemm_qkv(
    const __hip_bfloat16* __restrict__ A, const __hip_bfloat16* __restrict__ Wp,
    const float* __restrict__ b0, const float* __restrict__ b1, const float* __restrict__ b2,
    __hip_bfloat16* __restrict__ q, __hip_bfloat16* __restrict__ k, __hip_bfloat16* __restrict__ v,
    int N, int K) {
  __shared__ __align__(16) short sA[4 * 128 * 8];
  __shared__ __align__(16) short sB[4 * 128 * 8];
  int z = blockIdx.z;
  const __hip_bfloat16* W = Wp + (size_t)z * 589824;
  const float* bb = (z == 0) ? b0 : (z == 1) ? b1 : b2;
  void* C = (z == 0) ? (void*)q : (z == 1) ? (void*)k : (void*)v;
  gemm_core(sA, sB, A, W, bb, C, N, K, 0, K, true, GF_BF16OUT);
}

// ---------------- MFMA flash attention: block = (64 queries, h, b), 4 waves ----------------
// LDS tiles are [row][64] bf16 with 16B-granularity XOR swizzle (idx in shorts):
#define SWZ(r, c) ((((r) * 64) + (c)) ^ (((r) & 7) << 3))

__global__ __launch_bounds__(256) void attn_mfma(
    const __hip_bfloat16* __restrict__ q, const __hip_bfloat16* __restrict__ k,
    const __hip_bfloat16* __restrict__ v, const float* __restrict__ rel_emb,
    const int* __restrict__ rel_ids, const int* __restrict__ att_mask,
    __hip_bfloat16* __restrict__ ctx) {
  __shared__ __align__(16) short QsSs[64 * 64];  // Q tile, then reused for P tile
  __shared__ __align__(16) short Ks[64 * 64];
  __shared__ __align__(16) short Vt[64 * 64];    // transposed V: [d][j]
  __shared__ float relb[64 * 32];                // pre-scaled rel bias [i][r]

  int t = threadIdx.x;
  int w = t >> 6, lane = t & 63;
  int g = lane >> 4, l16 = lane & 15;
  int i0 = blockIdx.x * 64, h = blockIdx.y, b = blockIdx.z;

  // ---- stage Q tile, folding in the 1/8 softmax scale (exact in bf16) ----
  {
    int row = lane;
    const __hip_bfloat16* src = q + ((size_t)(b * S_ + i0 + row)) * D_ + h * DH_ + w * 16;
    uint4 u0 = *(const uint4*)src;
    uint4 u1 = *(const uint4*)(src + 8);
    const unsigned short* p0 = (const unsigned short*)&u0;
    const unsigned short* p1 = (const unsigned short*)&u1;
    short8 t0, t1;
#pragma unroll
    for (int e = 0; e < 8; ++e) t0[e] = (short)f2bu(u2f(p0[e]) * 0.125f);
#pragma unroll
    for (int e = 0; e < 8; ++e) t1[e] = (short)f2bu(u2f(p1[e]) * 0.125f);
    *(short8*)&QsSs[SWZ(row, w * 16)]     = t0;
    *(short8*)&QsSs[SWZ(row, w * 16 + 8)] = t1;
  }
  __syncthreads();

  // ---- per-wave Q fragments (rows w*16..w*16+15), hoisted for whole kernel ----
  short8 afq[2];
  afq[0] = *(short8*)&QsSs[SWZ(w * 16 + l16, 0 + g * 8)];
  afq[1] = *(short8*)&QsSs[SWZ(w * 16 + l16, 32 + g * 8)];

  // ---- rel bias table via MFMA: relb[i][r] = (Q/8)[i] . rel_emb[r][h] ----
  {
    floatx4 racc[2] = {};
#pragma unroll
    for (int rsub = 0; rsub < 2; ++rsub) {
      int r = rsub * 16 + l16;
#pragma unroll
      for (int ks = 0; ks < 2; ++ks) {
        const float* rp = rel_emb + ((size_t)r * H_ + h) * DH_ + ks * 32 + g * 8;
        short8 brf;
#pragma unroll
        for (int e = 0; e < 8; ++e) brf[e] = (short)f2bu(rp[e]);
        racc[rsub] = __builtin_amdgcn_mfma_f32_16x16x32_bf16(afq[ks], brf, racc[rsub], 0, 0, 0);
      }
    }
#pragma unroll
    for (int rsub = 0; rsub < 2; ++rsub)
#pragma unroll
      for (int rr = 0; rr < 4; ++rr)
        relb[(w * 16 + g * 4 + rr) * 32 + rsub * 16 + l16] = racc[rsub][rr];
  }
  __syncthreads();  // Q reads done -> QsSs becomes the P buffer

  float m_old[4] = {-1e30f, -1e30f, -1e30f, -1e30f};
  float lsum[4] = {0.0f, 0.0f, 0.0f, 0.0f};
  floatx4 oacc[4] = {};

  for (int jt = 0; jt < S_ / 64; ++jt) {
    int j0 = jt * 64;
    // stage K tile (row-major, swizzled)
    {
      int row = lane;
      const __hip_bfloat16* src = k + ((size_t)(b * S_ + j0 + row)) * D_ + h * DH_ + w * 16;
      uint4 u0 = *(const uint4*)src;
      uint4 u1 = *(const uint4*)(src + 8);
      *(uint4*)&Ks[SWZ(row, w * 16)]     = u0;
      *(uint4*)&Ks[SWZ(row, w * 16 + 8)] = u1;
    }
    // stage V transposed: wave w owns d-rows w*16..w*16+15; lanes span j -> one
    // contiguous 128B LDS row per scalar-store instruction (conflict-free)
    {
      int j = lane;
      const __hip_bfloat16* src = v + ((size_t)(b * S_ + j0 + j)) * D_ + h * DH_ + w * 16;
      uint4 u0 = *(const uint4*)src;
      uint4 u1 = *(const uint4*)(src + 8);
      const unsigned short* p0 = (const unsigned short*)&u0;
      const unsigned short* p1 = (const unsigned short*)&u1;
#pragma unroll
      for (int e = 0; e < 8; ++e) Vt[SWZ(w * 16 + e, j)] = (short)p0[e];
#pragma unroll
      for (int e = 0; e < 8; ++e) Vt[SWZ(w * 16 + 8 + e, j)] = (short)p1[e];
    }
    __syncthreads();

    // QK^T: wave's 16 i-rows x 64 j-cols, pre-scaled by 1/8 via Q
    floatx4 sacc[4] = {};
#pragma unroll
    for (int ks = 0; ks < 2; ++ks)
#pragma unroll
      for (int jm = 0; jm < 4; ++jm) {
        short8 bk = *(short8*)&Ks[SWZ(jm * 16 + l16, ks * 32 + g * 8)];
        sacc[jm] = __builtin_amdgcn_mfma_f32_16x16x32_bf16(afq[ks], bk, sacc[jm], 0, 0, 0);
      }

    // rel-bias gather + mask + online softmax; write P (bf16) into wave's Ss stripe
    float alpha[4];
#pragma unroll
    for (int r = 0; r < 4; ++r) {
      int gi = i0 + w * 16 + g * 4 + r;
      const int* ridp = rel_ids + ((size_t)(b * S_ + gi)) * S_ + j0 + l16;
      const int* amp  = att_mask + ((size_t)(b * S_ + gi)) * S_ + j0 + l16;
      const float* rbrow = relb + (w * 16 + g * 4 + r) * 32;
      float sv[4];
      float tmax = -3e38f;
#pragma unroll
      for (int jm = 0; jm < 4; ++jm) {
        int rid = ridp[jm * 16];
        int am  = amp[jm * 16];
        float sc = sacc[jm][r] + rbrow[rid] + (am ? 0.0f : -10000.0f);
        sv[jm] = sc;
        tmax = fmaxf(tmax, sc);
      }
#pragma unroll
      for (int off = 1; off < 16; off <<= 1) tmax = fmaxf(tmax, __shfl_xor(tmax, off));
      float mn = fmaxf(m_old[r], tmax);
      float al = __expf(m_old[r] - mn);
      m_old[r] = mn;
      float ps = 0.0f;
#pragma unroll
      for (int jm = 0; jm < 4; ++jm) {
        unsigned short pu = f2bu(__expf(sv[jm] - mn));
        QsSs[SWZ(w * 16 + g * 4 + r, jm * 16 + l16)] = (short)pu;
        ps += u2f(pu);  // lsum consistent with the bf16 P actually used in PV
      }
#pragma unroll
      for (int off = 1; off < 16; off <<= 1) ps += __shfl_xor(ps, off);
      lsum[r] = lsum[r] * al + ps;
      alpha[r] = al;
    }
#pragma unroll
    for (int dt = 0; dt < 4; ++dt)
#pragma unroll
      for (int r = 0; r < 4; ++r) oacc[dt][r] *= alpha[r];

    // PV: A = P (wave-private Ss stripe), B = Vt
#pragma unroll
    for (int ks = 0; ks < 2; ++ks) {
      short8 ap = *(short8*)&QsSs[SWZ(w * 16 + l16, ks * 32 + g * 8)];
#pragma unroll
      for (int dt = 0; dt < 4; ++dt) {
        short8 bv_ = *(short8*)&Vt[SWZ(dt * 16 + l16, ks * 32 + g * 8)];
        oacc[dt] = __builtin_amdgcn_mfma_f32_16x16x32_bf16(ap, bv_, oacc[dt], 0, 0, 0);
      }
    }
    __syncthreads();  // before next tile overwrites Ks/Vt
  }

  // normalize + store ctx (bf16)
#pragma unroll
  for (int r = 0; r < 4; ++r) {
    float inv = 1.0f / lsum[r];
    int gi = i0 + w * 16 + g * 4 + r;
    __hip_bfloat16* dst = ctx + ((size_t)(b * S_ + gi)) * D_ + h * DH_;
#pragma unroll
    for (int dt = 0; dt < 4; ++dt) {
      unsigned short pv = f2bu(oacc[dt][r] * inv);
      *(unsigned short*)&dst[dt * 16 + l16] = pv;
    }
  }
}

extern "C" void kernel_launch(void* const* d_in, const int* in_sizes, int n_in,
                              void* d_out, int out_size, void* d_ws, size_t ws_size,
                              hipStream_t stream) {
  const int* token_ids    = (const int*)d_in[0];
  const int* segment_ids  = (const int*)d_in[1];
  const int* position_ids = (const int*)d_in[2];
  const int* question_mask= (const int*)d_in[3];
  const int* att_mask     = (const int*)d_in[4];
  const int* rel_ids      = (const int*)d_in[5];
  const float* tok_emb = (const float*)d_in[6];
  const float* seg_emb = (const float*)d_in[7];
  const float* ln1_g = (const float*)d_in[8];
  const float* ln1_b = (const float*)d_in[9];
  const float* ln2_g = (const float*)d_in[10];
  const float* ln2_b = (const float*)d_in[11];
  const float* wq = (const float*)d_in[12];
  const float* bq = (const float*)d_in[13];
  const float* wk = (const float*)d_in[14];
  const float* bk = (const float*)d_in[15];
  const float* wv = (const float*)d_in[16];
  const float* bv = (const float*)d_in[17];
  const float* wo = (const float*)d_in[18];
  const float* bo = (const float*)d_in[19];
  const float* rel_emb = (const float*)d_in[20];
  const float* w1 = (const float*)d_in[21];
  const float* b1 = (const float*)d_in[22];
  const float* w2 = (const float*)d_in[23];
  const float* b2 = (const float*)d_in[24];

  const size_t NTOK = (size_t)B_ * S_ * D_;     // 1,572,864 elems
  const size_t BF = NTOK * 2;                   // bytes per bf16 activation

  float* x = (float*)d_out;                     // residual stream f32 in d_out
  char* ws = (char*)d_ws;
  __hip_bfloat16* h = (__hip_bfloat16*)(ws);
  __hip_bfloat16* q = (__hip_bfloat16*)(ws + BF);
  __hip_bfloat16* k = (__hip_bfloat16*)(ws + 2 * BF);
  __hip_bfloat16* v = (__hip_bfloat16*)(ws + 3 * BF);
  // ffn (B*S*F bf16 = 12.58MB) aliases q,k,v (dead during FFN) + 3.15MB
  __hip_bfloat16* ffn = (__hip_bfloat16*)(ws + BF);
  // per-layer prepacked weights: 13.5MB at ws+16MB (peak ws usage ~29.5MB)
  __hip_bfloat16* wp = (__hip_bfloat16*)(ws + ((size_t)16 << 20));

  embed_kernel<<<B_ * S_, 256, 0, stream>>>(token_ids, segment_ids, position_ids,
                                            question_mask, tok_emb, seg_emb, x);

  dim3 gQkv(D_ / 128, (B_ * S_) / 128, 3);      // (6, 16, 3)
  dim3 gWo(D_ / 128, (B_ * S_) / 128, 2);       // (6, 16, 2) split-K=2
  dim3 gFfn1(F_ / 128, (B_ * S_) / 128, 1);     // (24, 16)
  dim3 gFfn2(D_ / 128, (B_ * S_) / 128, 4);     // (6, 16, 4) split-K=4
  dim3 gAttn(S_ / 64, H_, B_);                  // (16, 12, 2)

  for (int l = 0; l < L_; ++l) {
    const float* wq_l = wq + (size_t)l * D_ * D_;
    const float* wk_l = wk + (size_t)l * D_ * D_;
    const float* wv_l = wv + (size_t)l * D_ * D_;
    const float* wo_l = wo + (size_t)l * D_ * D_;
    const float* w1_l = w1 + (size_t)l * D_ * F_;
    const float* w2_l = w2 + (size_t)l * F_ * D_;
    const float* re_l = rel_emb + (size_t)l * R_ * H_ * DH_;

    prepack<<<3456, 256, 0, stream>>>(wq_l, wk_l, wv_l, wo_l, w1_l, w2_l, wp);

    ln_kernel<<<B_ * S_, 256, 0, stream>>>(x, ln1_g + (size_t)l * D_, ln1_b + (size_t)l * D_, h);
    gemm_qkv<<<gQkv, 256, 0, stream>>>(h, wp,
                                       bq + (size_t)l * D_, bk + (size_t)l * D_, bv + (size_t)l * D_,
                                       q, k, v, D_, D_);
    attn_mfma<<<gAttn, 256, 0, stream>>>(q, k, v, re_l, rel_ids, att_mask, h);
    gemm_bf16<<<gWo, 256, 0, stream>>>(h, wp + WOFF_WO, bo + (size_t)l * D_, x,
                                       D_, D_, D_ / 2, GF_RES);
    ln_kernel<<<B_ * S_, 256, 0, stream>>>(x, ln2_g + (size_t)l * D_, ln2_b + (size_t)l * D_, h);
    gemm_bf16<<<gFfn1, 256, 0, stream>>>(h, wp + WOFF_W1, b1 + (size_t)l * F_, ffn,
                                         F_, D_, D_, GF_GELU | GF_BF16OUT);
    gemm_bf16<<<gFfn2, 256, 0, stream>>>(ffn, wp + WOFF_W2, b2 + (size_t)l * D_, x,
                                         D_, F_, F_ / 4, GF_RES);
  }
  // x == d_out (f32): done.
}